// Round 8
// baseline (423.422 us; speedup 1.0000x reference)
//
#include <hip/hip_runtime.h>

// B=2, S=4096, D=768, H=12, HD=64
#define Sq 4096
#define Dm 768
#define Hh 12
#define KD 768

typedef short short8 __attribute__((ext_vector_type(8)));
typedef float f32x4 __attribute__((ext_vector_type(4)));
typedef unsigned short bf_t;

__device__ inline bf_t f2bf(float f) {
    unsigned int u = __builtin_bit_cast(unsigned int, f);
    u += 0x7fffu + ((u >> 16) & 1u);   // RNE
    return (bf_t)(u >> 16);
}

// pack two fp32 -> bf16x2 (round-half-up: 1 add each + 1 v_perm) — HW-verified path
__device__ inline unsigned int pk2bf(float a, float b) {
    unsigned int ua = __builtin_bit_cast(unsigned int, a) + 0x8000u;
    unsigned int ub = __builtin_bit_cast(unsigned int, b) + 0x8000u;
    return __builtin_amdgcn_perm(ub, ua, 0x07060302);
}

__device__ inline float fexp2(float x) {
#if __has_builtin(__builtin_amdgcn_exp2f)
    return __builtin_amdgcn_exp2f(x);
#else
    return exp2f(x);
#endif
}

__device__ inline void gl_lds16(const void* g, void* l) {
    __builtin_amdgcn_global_load_lds(
        (const __attribute__((address_space(1))) unsigned int*)g,
        (__attribute__((address_space(3))) unsigned int*)l, 16, 0, 0);
}

// ---------------- fp32 -> bf16 convert, up to 4 arrays per launch ----------------
struct CvtJobs { const float* s[4]; bf_t* d[4]; };

__global__ __launch_bounds__(256) void cvt(CvtJobs jobs, int n) {
    const float* s = jobs.s[blockIdx.z];
    bf_t* d = jobs.d[blockIdx.z];
    int i = (blockIdx.x * 256 + threadIdx.x) * 8;
    if (i < n) {
        float4 a = *(const float4*)(s + i);
        float4 b = *(const float4*)(s + i + 4);
        short8 p;
        p[0] = (short)f2bf(a.x); p[1] = (short)f2bf(a.y);
        p[2] = (short)f2bf(a.z); p[3] = (short)f2bf(a.w);
        p[4] = (short)f2bf(b.x); p[5] = (short)f2bf(b.y);
        p[6] = (short)f2bf(b.z); p[7] = (short)f2bf(b.w);
        *(short8*)(d + i) = p;
    }
}

// ---------------- bf16 GEMM: C = A (MxK) * B^T (NxK) + bias ----------------
struct GemmJob {
    const bf_t* __restrict__ A; const bf_t* __restrict__ Bm;
    const float* __restrict__ bias; void* __restrict__ out;
    int mode; float scale;
};
struct GemmJobs { GemmJob j[3]; };

__global__ __launch_bounds__(256, 3) void gemm_k(GemmJobs jobs) {
    const GemmJob J = jobs.j[blockIdx.z];
    __shared__ bf_t As[128 * 64];
    __shared__ bf_t Bs[128 * 64];
    const int lane = threadIdx.x & 63, wv = threadIdx.x >> 6;
    const int l16 = lane & 15, quad = lane >> 4;
    const int wm = wv >> 1, wn = wv & 1;
    int m0, n0;
    if (J.mode == 1) { m0 = blockIdx.y * 128; n0 = blockIdx.x * 128; }
    else             { m0 = blockIdx.x * 128; n0 = blockIdx.y * 128; }

    f32x4 acc[4][4] = {};

    for (int kk = 0; kk < KD; kk += 64) {
#pragma unroll
        for (int it = 0; it < 4; ++it) {
            int p0 = it * 256 + wv * 64;
            int p = p0 + lane;
            int row = p >> 3;
            int c = (p & 7) ^ (row & 7);
            gl_lds16(J.A + (size_t)(m0 + row) * KD + kk + c * 8, As + p0 * 8);
            gl_lds16(J.Bm + (size_t)(n0 + row) * KD + kk + c * 8, Bs + p0 * 8);
        }
        __syncthreads();
#pragma unroll
        for (int ks = 0; ks < 2; ++ks) {
            short8 a[4], b[4];
#pragma unroll
            for (int i = 0; i < 4; ++i) {
                int row = wm * 64 + i * 16 + l16;
                int pc = (ks * 4 + quad) ^ (row & 7);
                a[i] = *(const short8*)&As[row * 64 + pc * 8];
            }
#pragma unroll
            for (int j = 0; j < 4; ++j) {
                int row = wn * 64 + j * 16 + l16;
                int pc = (ks * 4 + quad) ^ (row & 7);
                b[j] = *(const short8*)&Bs[row * 64 + pc * 8];
            }
#pragma unroll
            for (int i = 0; i < 4; ++i)
#pragma unroll
                for (int j = 0; j < 4; ++j)
                    acc[i][j] = __builtin_amdgcn_mfma_f32_16x16x32_bf16(a[i], b[j], acc[i][j], 0, 0, 0);
        }
        __syncthreads();
    }

#pragma unroll
    for (int i = 0; i < 4; ++i) {
#pragma unroll
        for (int j = 0; j < 4; ++j) {
            int grow = m0 + wm * 64 + i * 16 + quad * 4;
            int gcol = n0 + wn * 64 + j * 16 + l16;
            if (J.mode == 0) {
                float bv = J.bias[gcol];
                int h = gcol >> 6, hd = gcol & 63;
                bf_t* dst = (bf_t*)J.out;
#pragma unroll
                for (int r = 0; r < 4; ++r) {
                    int row = grow + r;
                    int bI = row >> 12, s = row & 4095;
                    dst[(((size_t)(bI * Hh + h) * Sq + s) << 6) + hd] =
                        f2bf((acc[i][j][r] + bv) * J.scale);
                }
            } else if (J.mode == 1) {
                // V^T TILE-CONTIGUOUS layout: [bh][kv-tile][feat 64][key 64]
                bf_t* dst = (bf_t*)J.out;
                int t = gcol, bI = t >> 12, s = t & 4095;
                size_t tb = (size_t)(bI * Hh) * Sq * 64;   // h added per r
#pragma unroll
                for (int r = 0; r < 4; ++r) {
                    int f = grow + r;
                    int h = f >> 6, hd = f & 63;
                    dst[tb + (size_t)h * Sq * 64 + (s >> 6) * 4096 + hd * 64 + (s & 63)] =
                        f2bf(acc[i][j][r] + J.bias[f]);
                }
            } else {
                float bv = J.bias[gcol];
                float* dst = (float*)J.out;
#pragma unroll
                for (int r = 0; r < 4; ++r)
                    dst[(size_t)(grow + r) * Dm + gcol] = acc[i][j][r] + bv;
            }
        }
    }
}

// ---------------- flash attention, causal, fixed-shift softmax ----------------
// Q,K: [B*H, S, 64] bf16 (Q pre-scaled by (1/8)*log2e).
// VT: [B*H, Sq/64, 64 feat, 64 key] bf16 (tile-contiguous).
// LDS-STAGED version (R0..R7 evidence: dur tracks total VMEM instruction
// work — per-wave private K/V loads saturate the per-CU TA/L1 path, which
// no PMC shows; waves/balance/layout changes were all null or negative).
//   block = 256 thr = 4 waves = 4 consecutive 64-row groups (256 q-rows),
//   walking ONE shared key stream. K/V tiles staged to LDS by the whole
//   block via global_load_lds (gemm_k's proven XOR-swizzle pattern),
//   double-buffered, 1 barrier/tile. Frag reads from LDS (swizzled,
//   conflict-free). Waves past their causal range skip compute but keep
//   staging+barriers (uniform). No key-split -> direct epilogue.
// NOTE: no min-occupancy arg in __launch_bounds__ (R3: (256,4) forced a
// 64-VGPR cap -> 2.3GB scratch spill).
#define SHIFT 18.0f
#define NQ 4

__global__ __launch_bounds__(256) void attn(const bf_t* __restrict__ Q,
                                            const bf_t* __restrict__ K,
                                            const bf_t* __restrict__ VT,
                                            bf_t* __restrict__ O) {
    const int bh = blockIdx.x;
    const int y = blockIdx.y;                       // 0..15
    const int lane = threadIdx.x & 63, rg = threadIdx.x >> 6;   // row-group 0..3
    const int l16 = lane & 15, quad = lane >> 4;
    const int b = bh / Hh, h = bh % Hh;
    const size_t base = (size_t)bh * Sq * 64;
    const int q0 = y * 256 + rg * 64;               // 64 rows per wave
    const int nkt_w = (q0 >> 6) + 1;                // tiles this wave computes
    const int kt_max = y * 4 + 4;                   // tiles the block stages

    __shared__ bf_t Ks[2][64 * 64];
    __shared__ bf_t Vs[2][64 * 64];

    const bf_t* __restrict__ Kb = K + base;
    const bf_t* __restrict__ Vb = VT + base;

    // Q as B-frags (n=qrow l16, k=quad*8+j)
    short8 qf[NQ][2];
#pragma unroll
    for (int i = 0; i < NQ; ++i) {
        const bf_t* qp = Q + base + (size_t)(q0 + i * 16 + l16) * 64 + quad * 8;
        qf[i][0] = *(const short8*)qp;
        qf[i][1] = *(const short8*)(qp + 32);
    }

    f32x4 oacc[NQ][4] = {};   // O^T: [i][feat quad*4+r] x [qrow l16]
    f32x4 lsum[NQ] = {};

    const int kroff = ((l16 >> 2) << 3) + (l16 & 3);   // permuted row offset

    short8 ones32;
#pragma unroll
    for (int j = 0; j < 8; ++j) ones32[j] = (short)0x3F80;

    // staging: tile = 64 rows x 64 cols bf16 (8 KB); 2 its x 256 thr x 16B.
    // LDS chunk j of row holds global chunk j^(row&7)  (gemm_k pattern).
#define STAGE(KT, BUF)                                                       \
    {                                                                        \
        const bf_t* Ksrc = Kb + (KT) * 4096;                                 \
        const bf_t* Vsrc = Vb + (KT) * 4096;                                 \
        _Pragma("unroll")                                                    \
        for (int it = 0; it < 2; ++it) {                                     \
            int p0 = it * 256 + rg * 64;                                     \
            int p = p0 + lane;                                               \
            int row = p >> 3;                                                \
            int c = (p & 7) ^ (row & 7);                                     \
            gl_lds16(Ksrc + row * 64 + c * 8, &Ks[BUF][p0 * 8]);             \
            gl_lds16(Vsrc + row * 64 + c * 8, &Vs[BUF][p0 * 8]);             \
        }                                                                    \
    }

    STAGE(0, 0);
    __syncthreads();

    int buf = 0;
    for (int kt = 0; kt < kt_max; ++kt) {
        const bool more = (kt + 1 < kt_max);
        if (more) STAGE(kt + 1, buf ^ 1);     // issue before compute (2-phase)

        if (kt < nkt_w) {
            const int kv0 = kt * 64;
            // K frags from LDS (permuted rows), t=2g+s
            short8 kf[4][2];
#pragma unroll
            for (int t = 0; t < 4; ++t) {
                int g = t >> 1, s = t & 1;
                int row = 32 * g + 4 * s + kroff;
                kf[t][0] = *(const short8*)&Ks[buf][row * 64 + ((quad) ^ (row & 7)) * 8];
                kf[t][1] = *(const short8*)&Ks[buf][row * 64 + ((4 + quad) ^ (row & 7)) * 8];
            }
            // V frags from LDS [feat][key]
            short8 vfr[4][2];
#pragma unroll
            for (int ot = 0; ot < 4; ++ot) {
                int row = ot * 16 + l16;
#pragma unroll
                for (int g = 0; g < 2; ++g)
                    vfr[ot][g] = *(const short8*)&Vs[buf][row * 64 + ((4 * g + quad) ^ (row & 7)) * 8];
            }
#pragma unroll
            for (int i = 0; i < NQ; ++i) {
                // QK: S^T tiles, permuted key order; C-init carries the -SHIFT
                f32x4 st[4];
#pragma unroll
                for (int t = 0; t < 4; ++t) {
                    f32x4 z = {-SHIFT, -SHIFT, -SHIFT, -SHIFT};
                    z = __builtin_amdgcn_mfma_f32_16x16x32_bf16(kf[t][0], qf[i][0], z, 0, 0, 0);
                    st[t] = __builtin_amdgcn_mfma_f32_16x16x32_bf16(kf[t][1], qf[i][1], z, 0, 0, 0);
                }
                // mask + exp2 + pack (permuted key = kv0+32g+8*quad+4s+r)
                alignas(16) unsigned int pkd[4][2];
                const bool need_mask = (kv0 + 63 > q0 + i * 16);
#pragma unroll
                for (int t = 0; t < 4; ++t) {
                    int g = t >> 1, s = t & 1;
                    f32x4 sv = st[t];
                    if (need_mask) {
                        int qrow = q0 + i * 16 + l16;
                        int kb2 = kv0 + 32 * g + 8 * quad + 4 * s;
#pragma unroll
                        for (int r = 0; r < 4; ++r)
                            if (kb2 + r > qrow) sv[r] = -1e30f;
                    }
                    pkd[t][0] = pk2bf(fexp2(sv[0]), fexp2(sv[1]));
                    pkd[t][1] = pk2bf(fexp2(sv[2]), fexp2(sv[3]));
                }
                // PV: B-frag direct from pkd, K=32
#pragma unroll
                for (int g = 0; g < 2; ++g) {
                    short8 pf = *(const short8*)&pkd[2 * g][0];
                    lsum[i] = __builtin_amdgcn_mfma_f32_16x16x32_bf16(ones32, pf, lsum[i], 0, 0, 0);
#pragma unroll
                    for (int ot = 0; ot < 4; ++ot)
                        oacc[i][ot] = __builtin_amdgcn_mfma_f32_16x16x32_bf16(vfr[ot][g], pf, oacc[i][ot], 0, 0, 0);
                }
            }
        }
        __syncthreads();   // stage(kt+1) landed; all waves done with buf
        buf ^= 1;
    }
#undef STAGE

    // epilogue: O^T C-layout -> [B,S,D] bf16; 4 contiguous feats/lane -> 8B stores
#pragma unroll
    for (int i = 0; i < NQ; ++i) {
        float inv = 1.0f / lsum[i][0];
        int srow = q0 + i * 16 + l16;
        bf_t* orow = O + (size_t)(b * Sq + srow) * Dm + h * 64;
#pragma unroll
        for (int ot = 0; ot < 4; ++ot) {
            uint2 pk;
            pk.x = pk2bf(oacc[i][ot][0] * inv, oacc[i][ot][1] * inv);
            pk.y = pk2bf(oacc[i][ot][2] * inv, oacc[i][ot][3] * inv);
            *(uint2*)(orow + ot * 16 + quad * 4) = pk;
        }
    }
}

extern "C" void kernel_launch(void* const* d_in, const int* in_sizes, int n_in,
                              void* d_out, int out_size, void* d_ws, size_t ws_size,
                              hipStream_t stream) {
    const float* q  = (const float*)d_in[0];
    const float* k  = (const float*)d_in[1];
    const float* v  = (const float*)d_in[2];
    // d_in[3]: causal mask — analytic
    const float* Wq = (const float*)d_in[4];  const float* bq = (const float*)d_in[5];
    const float* Wk = (const float*)d_in[6];  const float* bk = (const float*)d_in[7];
    const float* Wv = (const float*)d_in[8];  const float* bv = (const float*)d_in[9];
    const float* Wo = (const float*)d_in[10]; const float* bo = (const float*)d_in[11];
    float* out = (float*)d_out;

    const float QSCALE = 0.125f * 1.44269504f;     // (1/sqrt(64)) * log2(e)

    const size_t NTOK = (size_t)2 * Sq * Dm;   // 6291456
    const size_t NW   = (size_t)Dm * Dm;       // 589824
    dim3 b256(256);

    const size_t need_main = (6 * NTOK + 4 * NW) * 2;   // 80.2 MB

    if (ws_size >= need_main) {
        bf_t* qb  = (bf_t*)d_ws;
        bf_t* kb  = qb + NTOK;
        bf_t* vb  = kb + NTOK;
        bf_t* xq  = vb + NTOK;
        bf_t* xk  = xq + NTOK;
        bf_t* xv  = xk + NTOK;
        bf_t* wqb = xv + NTOK;
        bf_t* wkb = wqb + NW;
        bf_t* wvb = wkb + NW;
        bf_t* wob = wvb + NW;
        bf_t* ob  = xq;

        CvtJobs cw = {{Wq, Wk, Wv, Wo}, {wqb, wkb, wvb, wob}};
        cvt<<<dim3(288, 1, 4), b256, 0, stream>>>(cw, (int)NW);
        CvtJobs cx = {{q, k, v, q}, {xq, xk, xv, xq}};
        cvt<<<dim3(3072, 1, 3), b256, 0, stream>>>(cx, (int)NTOK);

        GemmJobs gp;
        gp.j[0] = {xq,  wqb, bq, qb, 0, QSCALE};
        gp.j[1] = {xk,  wkb, bk, kb, 0, 1.0f};
        gp.j[2] = {wvb, xv,  bv, vb, 1, 1.0f};     // V^T direct (tile-contiguous)
        gemm_k<<<dim3(64, 6, 3), b256, 0, stream>>>(gp);

        attn<<<dim3(2 * Hh, Sq / 256), b256, 0, stream>>>(qb, kb, vb, ob);

        GemmJobs go;
        go.j[0] = {ob, wob, bo, out, 2, 1.0f};
        go.j[1] = go.j[0]; go.j[2] = go.j[0];
        gemm_k<<<dim3(64, 6, 1), b256, 0, stream>>>(go);
    } else {
        bf_t* qb  = (bf_t*)d_ws;
        bf_t* kb  = qb + NTOK;
        bf_t* vb  = kb + NTOK;
        bf_t* ob  = vb + NTOK;
        bf_t* xc  = ob + NTOK;
        bf_t* wqb = xc + NTOK;
        bf_t* wkb = wqb + NW;
        bf_t* wvb = wkb + NW;
        bf_t* wob = wvb + NW;

        CvtJobs cw = {{Wq, Wk, Wv, Wo}, {wqb, wkb, wvb, wob}};
        cvt<<<dim3(288, 1, 4), b256, 0, stream>>>(cw, (int)NW);

        GemmJobs gj;
        CvtJobs c1 = {{q, q, q, q}, {xc, xc, xc, xc}};
        cvt<<<dim3(3072, 1, 1), b256, 0, stream>>>(c1, (int)NTOK);
        gj.j[0] = {xc, wqb, bq, qb, 0, QSCALE}; gj.j[1] = gj.j[0]; gj.j[2] = gj.j[0];
        gemm_k<<<dim3(64, 6, 1), b256, 0, stream>>>(gj);

        CvtJobs c2 = {{k, k, k, k}, {xc, xc, xc, xc}};
        cvt<<<dim3(3072, 1, 1), b256, 0, stream>>>(c2, (int)NTOK);
        gj.j[0] = {xc, wkb, bk, kb, 0, 1.0f}; gj.j[1] = gj.j[0]; gj.j[2] = gj.j[0];
        gemm_k<<<dim3(64, 6, 1), b256, 0, stream>>>(gj);

        CvtJobs c3 = {{v, v, v, v}, {xc, xc, xc, xc}};
        cvt<<<dim3(3072, 1, 1), b256, 0, stream>>>(c3, (int)NTOK);
        gj.j[0] = {wvb, xc, bv, vb, 1, 1.0f}; gj.j[1] = gj.j[0]; gj.j[2] = gj.j[0];
        gemm_k<<<dim3(64, 6, 1), b256, 0, stream>>>(gj);

        attn<<<dim3(2 * Hh, Sq / 256), b256, 0, stream>>>(qb, kb, vb, ob);

        gj.j[0] = {ob, wob, bo, out, 2, 1.0f}; gj.j[1] = gj.j[0]; gj.j[2] = gj.j[0];
        gemm_k<<<dim3(64, 6, 1), b256, 0, stream>>>(gj);
    }
}

// Round 9
// 366.987 us; speedup vs baseline: 1.1538x; 1.1538x over previous
//
#include <hip/hip_runtime.h>

// B=2, S=4096, D=768, H=12, HD=64
#define Sq 4096
#define Dm 768
#define Hh 12
#define KD 768

typedef short short8 __attribute__((ext_vector_type(8)));
typedef float f32x4 __attribute__((ext_vector_type(4)));
typedef unsigned short bf_t;

__device__ inline bf_t f2bf(float f) {
    unsigned int u = __builtin_bit_cast(unsigned int, f);
    u += 0x7fffu + ((u >> 16) & 1u);   // RNE
    return (bf_t)(u >> 16);
}

// pack two fp32 -> bf16x2 (round-half-up: 1 add each + 1 v_perm) — HW-verified path
__device__ inline unsigned int pk2bf(float a, float b) {
    unsigned int ua = __builtin_bit_cast(unsigned int, a) + 0x8000u;
    unsigned int ub = __builtin_bit_cast(unsigned int, b) + 0x8000u;
    return __builtin_amdgcn_perm(ub, ua, 0x07060302);
}

__device__ inline float fexp2(float x) {
#if __has_builtin(__builtin_amdgcn_exp2f)
    return __builtin_amdgcn_exp2f(x);
#else
    return exp2f(x);
#endif
}

__device__ inline void gl_lds16(const void* g, void* l) {
    __builtin_amdgcn_global_load_lds(
        (const __attribute__((address_space(1))) unsigned int*)g,
        (__attribute__((address_space(3))) unsigned int*)l, 16, 0, 0);
}

// ---------------- fp32 -> bf16 convert, up to 4 arrays per launch ----------------
struct CvtJobs { const float* s[4]; bf_t* d[4]; };

__global__ __launch_bounds__(256) void cvt(CvtJobs jobs, int n) {
    const float* s = jobs.s[blockIdx.z];
    bf_t* d = jobs.d[blockIdx.z];
    int i = (blockIdx.x * 256 + threadIdx.x) * 8;
    if (i < n) {
        float4 a = *(const float4*)(s + i);
        float4 b = *(const float4*)(s + i + 4);
        short8 p;
        p[0] = (short)f2bf(a.x); p[1] = (short)f2bf(a.y);
        p[2] = (short)f2bf(a.z); p[3] = (short)f2bf(a.w);
        p[4] = (short)f2bf(b.x); p[5] = (short)f2bf(b.y);
        p[6] = (short)f2bf(b.z); p[7] = (short)f2bf(b.w);
        *(short8*)(d + i) = p;
    }
}

// ---------------- bf16 GEMM: C = A (MxK) * B^T (NxK) + bias ----------------
struct GemmJob {
    const bf_t* __restrict__ A; const bf_t* __restrict__ Bm;
    const float* __restrict__ bias; void* __restrict__ out;
    int mode; float scale;
};
struct GemmJobs { GemmJob j[3]; };

__global__ __launch_bounds__(256, 3) void gemm_k(GemmJobs jobs) {
    const GemmJob J = jobs.j[blockIdx.z];
    __shared__ bf_t As[128 * 64];
    __shared__ bf_t Bs[128 * 64];
    const int lane = threadIdx.x & 63, wv = threadIdx.x >> 6;
    const int l16 = lane & 15, quad = lane >> 4;
    const int wm = wv >> 1, wn = wv & 1;
    int m0, n0;
    if (J.mode == 1) { m0 = blockIdx.y * 128; n0 = blockIdx.x * 128; }
    else             { m0 = blockIdx.x * 128; n0 = blockIdx.y * 128; }

    f32x4 acc[4][4] = {};

    for (int kk = 0; kk < KD; kk += 64) {
#pragma unroll
        for (int it = 0; it < 4; ++it) {
            int p0 = it * 256 + wv * 64;
            int p = p0 + lane;
            int row = p >> 3;
            int c = (p & 7) ^ (row & 7);
            gl_lds16(J.A + (size_t)(m0 + row) * KD + kk + c * 8, As + p0 * 8);
            gl_lds16(J.Bm + (size_t)(n0 + row) * KD + kk + c * 8, Bs + p0 * 8);
        }
        __syncthreads();
#pragma unroll
        for (int ks = 0; ks < 2; ++ks) {
            short8 a[4], b[4];
#pragma unroll
            for (int i = 0; i < 4; ++i) {
                int row = wm * 64 + i * 16 + l16;
                int pc = (ks * 4 + quad) ^ (row & 7);
                a[i] = *(const short8*)&As[row * 64 + pc * 8];
            }
#pragma unroll
            for (int j = 0; j < 4; ++j) {
                int row = wn * 64 + j * 16 + l16;
                int pc = (ks * 4 + quad) ^ (row & 7);
                b[j] = *(const short8*)&Bs[row * 64 + pc * 8];
            }
#pragma unroll
            for (int i = 0; i < 4; ++i)
#pragma unroll
                for (int j = 0; j < 4; ++j)
                    acc[i][j] = __builtin_amdgcn_mfma_f32_16x16x32_bf16(a[i], b[j], acc[i][j], 0, 0, 0);
        }
        __syncthreads();
    }

#pragma unroll
    for (int i = 0; i < 4; ++i) {
#pragma unroll
        for (int j = 0; j < 4; ++j) {
            int grow = m0 + wm * 64 + i * 16 + quad * 4;
            int gcol = n0 + wn * 64 + j * 16 + l16;
            if (J.mode == 0) {
                float bv = J.bias[gcol];
                int h = gcol >> 6, hd = gcol & 63;
                bf_t* dst = (bf_t*)J.out;
#pragma unroll
                for (int r = 0; r < 4; ++r) {
                    int row = grow + r;
                    int bI = row >> 12, s = row & 4095;
                    dst[(((size_t)(bI * Hh + h) * Sq + s) << 6) + hd] =
                        f2bf((acc[i][j][r] + bv) * J.scale);
                }
            } else if (J.mode == 1) {
                // V^T TILE-CONTIGUOUS layout: [bh][kv-tile][feat 64][key 64]
                bf_t* dst = (bf_t*)J.out;
                int t = gcol, bI = t >> 12, s = t & 4095;
                size_t tb = (size_t)(bI * Hh) * Sq * 64;   // h added per r
#pragma unroll
                for (int r = 0; r < 4; ++r) {
                    int f = grow + r;
                    int h = f >> 6, hd = f & 63;
                    dst[tb + (size_t)h * Sq * 64 + (s >> 6) * 4096 + hd * 64 + (s & 63)] =
                        f2bf(acc[i][j][r] + J.bias[f]);
                }
            } else {
                float bv = J.bias[gcol];
                float* dst = (float*)J.out;
#pragma unroll
                for (int r = 0; r < 4; ++r)
                    dst[(size_t)(grow + r) * Dm + gcol] = acc[i][j][r] + bv;
            }
        }
    }
}

// ---------------- flash attention, causal, fixed-shift softmax ----------------
// Q,K: [B*H, S, 64] bf16 (Q pre-scaled by (1/8)*log2e).
// VT: [B*H, Sq/64, 64 feat, 64 key] bf16 (tile-contiguous).
// R6 structure (best measured: 139 µs): 64 q-rows/wave (NQ=4), block = 4
// waves = {row-group 0/1} x {key-split 0/1}, private register K/V loads with
// WAR prefetch, fixed-shift partials combined by pure addition via LDS.
// NEW (R9): XCD-AWARE BLOCK SWIZZLE — grid (24,32) dispatched x-fast put all
// 24 heads' K/V streams on every XCD (24 MB >> 4 MB L2 -> evictions; per-tile
// VMEM latency is the measured bottleneck). Remap so each XCD owns exactly
// 3 heads (3 MB K+V, L2-resident): id = bx + 24*by; xcd = id&7; slot = id>>3;
// bh = 3*xcd + slot%3; y = slot/3. Bijective (768 = 8*96); 96 blocks/XCD =
// 3/CU. Correctness is mapping-independent (G16).
// NOTE: no min-occupancy arg in __launch_bounds__ (R3: (256,4) forced a
// 64-VGPR cap -> 2.3GB scratch spill).
#define SHIFT 18.0f
#define NQ 4

__global__ __launch_bounds__(256) void attn(const bf_t* __restrict__ Q,
                                            const bf_t* __restrict__ K,
                                            const bf_t* __restrict__ VT,
                                            bf_t* __restrict__ O) {
    // XCD-aware swizzle: each XCD gets 3 consecutive heads, all 32 q-tiles
    const int id = blockIdx.x + 24 * blockIdx.y;
    const int xcd = id & 7, slot = id >> 3;        // slot 0..95
    const int bh = xcd * 3 + slot % 3;
    const int qt = 31 - slot / 3;                  // long blocks first
    const int lane = threadIdx.x & 63, wv = threadIdx.x >> 6;   // wv 0..3
    const int rg = wv & 1, ksp = wv >> 1;          // row-group, key-split
    const int l16 = lane & 15, quad = lane >> 4;
    const int b = bh / Hh, h = bh % Hh;
    const size_t base = (size_t)bh * Sq * 64;
    const int q0 = qt * 128 + rg * 64;             // 64 rows per wave

    __shared__ float ocomb[2][64][68];             // [rg][row][feat] fp32, padded
    __shared__ float lcomb[2][64];

    const bf_t* __restrict__ Kb = K + base;
    const bf_t* __restrict__ Vb = VT + base;

    // Q as B-frags (n=qrow l16, k=quad*8+j)
    short8 qf[NQ][2];
#pragma unroll
    for (int i = 0; i < NQ; ++i) {
        const bf_t* qp = Q + base + (size_t)(q0 + i * 16 + l16) * 64 + quad * 8;
        qf[i][0] = *(const short8*)qp;
        qf[i][1] = *(const short8*)(qp + 32);
    }

    f32x4 oacc[NQ][4] = {};   // O^T: [i][feat quad*4+r] x [qrow l16]
    f32x4 lsum[NQ] = {};

    const int nkt = (q0 >> 6) + 1;
    const int hsp = (nkt + 1) >> 1;
    const int kt0 = ksp ? hsp : 0;
    const int kt1 = ksp ? nkt : hsp;

    const int kroff = ((l16 >> 2) << 3) + (l16 & 3);   // permuted row offset

    short8 ones32;
#pragma unroll
    for (int j = 0; j < 8; ++j) ones32[j] = (short)0x3F80;

    short8 kf[4][2];   // K tiles (permuted rows), t=2g+s
    short8 vfr[4][2];  // V frags [ot][g], 16B contiguous

    // 32-bit element offsets from Kb / Vb, advanced by constants per tile
    int ko = kroff * 64 + quad * 8 + kt0 * 4096;   // K: +(32g+4s)*64 per sub-tile
    int vo = l16 * 64 + quad * 8 + kt0 * 4096;     // V: +ot*1024 + 32g per frag

#define LOAD_K()                                                             \
    {                                                                        \
        _Pragma("unroll")                                                    \
        for (int g = 0; g < 2; ++g)                                          \
            _Pragma("unroll")                                                \
            for (int s = 0; s < 2; ++s) {                                    \
                const bf_t* kp = Kb + ko + (32 * g + 4 * s) * 64;            \
                kf[2 * g + s][0] = *(const short8*)kp;                       \
                kf[2 * g + s][1] = *(const short8*)(kp + 32);                \
            }                                                                \
    }
#define LOAD_V()                                                             \
    {                                                                        \
        _Pragma("unroll")                                                    \
        for (int ot = 0; ot < 4; ++ot)                                       \
            _Pragma("unroll")                                                \
            for (int g = 0; g < 2; ++g)                                      \
                vfr[ot][g] = *(const short8*)(Vb + vo + ot * 1024 + 32 * g); \
    }

    if (kt0 < kt1) { LOAD_K(); LOAD_V(); }

    for (int kt = kt0; kt < kt1; ++kt) {
        const int kv0 = kt * 64;
        const bool more = (kt + 1 < kt1);
#pragma unroll
        for (int i = 0; i < NQ; ++i) {
            // QK: S^T tiles, permuted key order; C-init carries the -SHIFT
            f32x4 st[4];
#pragma unroll
            for (int t = 0; t < 4; ++t) {
                f32x4 z = {-SHIFT, -SHIFT, -SHIFT, -SHIFT};
                z = __builtin_amdgcn_mfma_f32_16x16x32_bf16(kf[t][0], qf[i][0], z, 0, 0, 0);
                st[t] = __builtin_amdgcn_mfma_f32_16x16x32_bf16(kf[t][1], qf[i][1], z, 0, 0, 0);
            }
            if (i == NQ - 1) { ko += 4096; if (more) LOAD_K(); }   // WAR: after last QK use

            // mask + exp2 + pack (permuted key = kv0+32g+8*quad+4s+r)
            alignas(16) unsigned int pkd[4][2];
            const bool need_mask = (kv0 + 63 > q0 + i * 16);
#pragma unroll
            for (int t = 0; t < 4; ++t) {
                int g = t >> 1, s = t & 1;
                f32x4 sv = st[t];
                if (need_mask) {
                    int qrow = q0 + i * 16 + l16;
                    int kb2 = kv0 + 32 * g + 8 * quad + 4 * s;
#pragma unroll
                    for (int r = 0; r < 4; ++r)
                        if (kb2 + r > qrow) sv[r] = -1e30f;
                }
                pkd[t][0] = pk2bf(fexp2(sv[0]), fexp2(sv[1]));
                pkd[t][1] = pk2bf(fexp2(sv[2]), fexp2(sv[3]));
            }
            // PV: B-frag direct from pkd, K=32
#pragma unroll
            for (int g = 0; g < 2; ++g) {
                short8 pf = *(const short8*)&pkd[2 * g][0];
                lsum[i] = __builtin_amdgcn_mfma_f32_16x16x32_bf16(ones32, pf, lsum[i], 0, 0, 0);
#pragma unroll
                for (int ot = 0; ot < 4; ++ot)
                    oacc[i][ot] = __builtin_amdgcn_mfma_f32_16x16x32_bf16(vfr[ot][g], pf, oacc[i][ot], 0, 0, 0);
            }
        }
        vo += 4096;
        if (more) LOAD_V();   // WAR: issues after PV, lands during next QK+exp
    }
#undef LOAD_K
#undef LOAD_V

    // combine partials: split-1 writes, barrier, split-0 adds + epilogue
    if (ksp) {
#pragma unroll
        for (int i = 0; i < NQ; ++i) {
            int row = i * 16 + l16;
#pragma unroll
            for (int ot = 0; ot < 4; ++ot)
                *(f32x4*)&ocomb[rg][row][ot * 16 + quad * 4] = oacc[i][ot];
            if (quad == 0) lcomb[rg][row] = lsum[i][0];
        }
    }
    __syncthreads();
    if (!ksp) {
#pragma unroll
        for (int i = 0; i < NQ; ++i) {
            int row = i * 16 + l16;
            float ls = lsum[i][0] + lcomb[rg][row];
            float inv = 1.0f / ls;
            int srow = q0 + row;
            bf_t* orow = O + (size_t)(b * Sq + srow) * Dm + h * 64;
#pragma unroll
            for (int ot = 0; ot < 4; ++ot) {
                f32x4 oc = *(const f32x4*)&ocomb[rg][row][ot * 16 + quad * 4];
                uint2 pk;
                pk.x = pk2bf((oacc[i][ot][0] + oc[0]) * inv, (oacc[i][ot][1] + oc[1]) * inv);
                pk.y = pk2bf((oacc[i][ot][2] + oc[2]) * inv, (oacc[i][ot][3] + oc[3]) * inv);
                *(uint2*)(orow + ot * 16 + quad * 4) = pk;
            }
        }
    }
}

extern "C" void kernel_launch(void* const* d_in, const int* in_sizes, int n_in,
                              void* d_out, int out_size, void* d_ws, size_t ws_size,
                              hipStream_t stream) {
    const float* q  = (const float*)d_in[0];
    const float* k  = (const float*)d_in[1];
    const float* v  = (const float*)d_in[2];
    // d_in[3]: causal mask — analytic
    const float* Wq = (const float*)d_in[4];  const float* bq = (const float*)d_in[5];
    const float* Wk = (const float*)d_in[6];  const float* bk = (const float*)d_in[7];
    const float* Wv = (const float*)d_in[8];  const float* bv = (const float*)d_in[9];
    const float* Wo = (const float*)d_in[10]; const float* bo = (const float*)d_in[11];
    float* out = (float*)d_out;

    const float QSCALE = 0.125f * 1.44269504f;     // (1/sqrt(64)) * log2(e)

    const size_t NTOK = (size_t)2 * Sq * Dm;   // 6291456
    const size_t NW   = (size_t)Dm * Dm;       // 589824
    dim3 b256(256);

    const size_t need_main = (6 * NTOK + 4 * NW) * 2;   // 80.2 MB

    if (ws_size >= need_main) {
        bf_t* qb  = (bf_t*)d_ws;
        bf_t* kb  = qb + NTOK;
        bf_t* vb  = kb + NTOK;
        bf_t* xq  = vb + NTOK;
        bf_t* xk  = xq + NTOK;
        bf_t* xv  = xk + NTOK;
        bf_t* wqb = xv + NTOK;
        bf_t* wkb = wqb + NW;
        bf_t* wvb = wkb + NW;
        bf_t* wob = wvb + NW;
        bf_t* ob  = xq;

        CvtJobs cw = {{Wq, Wk, Wv, Wo}, {wqb, wkb, wvb, wob}};
        cvt<<<dim3(288, 1, 4), b256, 0, stream>>>(cw, (int)NW);
        CvtJobs cx = {{q, k, v, q}, {xq, xk, xv, xq}};
        cvt<<<dim3(3072, 1, 3), b256, 0, stream>>>(cx, (int)NTOK);

        GemmJobs gp;
        gp.j[0] = {xq,  wqb, bq, qb, 0, QSCALE};
        gp.j[1] = {xk,  wkb, bk, kb, 0, 1.0f};
        gp.j[2] = {wvb, xv,  bv, vb, 1, 1.0f};     // V^T direct (tile-contiguous)
        gemm_k<<<dim3(64, 6, 3), b256, 0, stream>>>(gp);

        attn<<<dim3(2 * Hh, Sq / 128), b256, 0, stream>>>(qb, kb, vb, ob);

        GemmJobs go;
        go.j[0] = {ob, wob, bo, out, 2, 1.0f};
        go.j[1] = go.j[0]; go.j[2] = go.j[0];
        gemm_k<<<dim3(64, 6, 1), b256, 0, stream>>>(go);
    } else {
        bf_t* qb  = (bf_t*)d_ws;
        bf_t* kb  = qb + NTOK;
        bf_t* vb  = kb + NTOK;
        bf_t* ob  = vb + NTOK;
        bf_t* xc  = ob + NTOK;
        bf_t* wqb = xc + NTOK;
        bf_t* wkb = wqb + NW;
        bf_t* wvb = wkb + NW;
        bf_t* wob = wvb + NW;

        CvtJobs cw = {{Wq, Wk, Wv, Wo}, {wqb, wkb, wvb, wob}};
        cvt<<<dim3(288, 1, 4), b256, 0, stream>>>(cw, (int)NW);

        GemmJobs gj;
        CvtJobs c1 = {{q, q, q, q}, {xc, xc, xc, xc}};
        cvt<<<dim3(3072, 1, 1), b256, 0, stream>>>(c1, (int)NTOK);
        gj.j[0] = {xc, wqb, bq, qb, 0, QSCALE}; gj.j[1] = gj.j[0]; gj.j[2] = gj.j[0];
        gemm_k<<<dim3(64, 6, 1), b256, 0, stream>>>(gj);

        CvtJobs c2 = {{k, k, k, k}, {xc, xc, xc, xc}};
        cvt<<<dim3(3072, 1, 1), b256, 0, stream>>>(c2, (int)NTOK);
        gj.j[0] = {xc, wkb, bk, kb, 0, 1.0f}; gj.j[1] = gj.j[0]; gj.j[2] = gj.j[0];
        gemm_k<<<dim3(64, 6, 1), b256, 0, stream>>>(gj);

        CvtJobs c3 = {{v, v, v, v}, {xc, xc, xc, xc}};
        cvt<<<dim3(3072, 1, 1), b256, 0, stream>>>(c3, (int)NTOK);
        gj.j[0] = {wvb, xc, bv, vb, 1, 1.0f}; gj.j[1] = gj.j[0]; gj.j[2] = gj.j[0];
        gemm_k<<<dim3(64, 6, 1), b256, 0, stream>>>(gj);

        attn<<<dim3(2 * Hh, Sq / 128), b256, 0, stream>>>(qb, kb, vb, ob);

        gj.j[0] = {ob, wob, bo, out, 2, 1.0f}; gj.j[1] = gj.j[0]; gj.j[2] = gj.j[0];
        gemm_k<<<dim3(64, 6, 1), b256, 0, stream>>>(gj);
    }
}

// Round 10
// 365.925 us; speedup vs baseline: 1.1571x; 1.0029x over previous
//
#include <hip/hip_runtime.h>

// B=2, S=4096, D=768, H=12, HD=64
#define Sq 4096
#define Dm 768
#define Hh 12
#define KD 768

typedef short short8 __attribute__((ext_vector_type(8)));
typedef float f32x4 __attribute__((ext_vector_type(4)));
typedef unsigned short bf_t;

__device__ inline bf_t f2bf(float f) {
    unsigned int u = __builtin_bit_cast(unsigned int, f);
    u += 0x7fffu + ((u >> 16) & 1u);   // RNE
    return (bf_t)(u >> 16);
}

// pack two fp32 -> bf16x2 (round-half-up: 1 add each + 1 v_perm) — HW-verified path
__device__ inline unsigned int pk2bf(float a, float b) {
    unsigned int ua = __builtin_bit_cast(unsigned int, a) + 0x8000u;
    unsigned int ub = __builtin_bit_cast(unsigned int, b) + 0x8000u;
    return __builtin_amdgcn_perm(ub, ua, 0x07060302);
}

__device__ inline float fexp2(float x) {
#if __has_builtin(__builtin_amdgcn_exp2f)
    return __builtin_amdgcn_exp2f(x);
#else
    return exp2f(x);
#endif
}

__device__ inline void gl_lds16(const void* g, void* l) {
    __builtin_amdgcn_global_load_lds(
        (const __attribute__((address_space(1))) unsigned int*)g,
        (__attribute__((address_space(3))) unsigned int*)l, 16, 0, 0);
}

// ---------------- fp32 -> bf16 convert, up to 8 arrays per launch ----------------
// Per-job element count n[z]; blocks beyond n/2048 early-exit (lets small
// weight jobs share one launch with the big input jobs).
struct CvtJobs { const float* s[8]; bf_t* d[8]; int n[8]; };

__global__ __launch_bounds__(256) void cvt(CvtJobs jobs) {
    const float* s = jobs.s[blockIdx.z];
    bf_t* d = jobs.d[blockIdx.z];
    int n = jobs.n[blockIdx.z];
    int i = (blockIdx.x * 256 + threadIdx.x) * 8;
    if (i < n) {
        float4 a = *(const float4*)(s + i);
        float4 b = *(const float4*)(s + i + 4);
        short8 p;
        p[0] = (short)f2bf(a.x); p[1] = (short)f2bf(a.y);
        p[2] = (short)f2bf(a.z); p[3] = (short)f2bf(a.w);
        p[4] = (short)f2bf(b.x); p[5] = (short)f2bf(b.y);
        p[6] = (short)f2bf(b.z); p[7] = (short)f2bf(b.w);
        *(short8*)(d + i) = p;
    }
}

// ---------------- bf16 GEMM: C = A (MxK) * B^T (NxK) + bias ----------------
struct GemmJob {
    const bf_t* __restrict__ A; const bf_t* __restrict__ Bm;
    const float* __restrict__ bias; void* __restrict__ out;
    int mode; float scale;
};
struct GemmJobs { GemmJob j[3]; };

// NOTE: plain __launch_bounds__(256) — the former (256,3) pinned 3 blocks/CU;
// without the min-occupancy arg the compiler's ~110 VGPR allows 4 blocks/CU,
// cutting the 1152-block proj launch from 1.5 to 1.125 scheduling rounds.
__global__ __launch_bounds__(256) void gemm_k(GemmJobs jobs) {
    const GemmJob J = jobs.j[blockIdx.z];
    __shared__ bf_t As[128 * 64];
    __shared__ bf_t Bs[128 * 64];
    const int lane = threadIdx.x & 63, wv = threadIdx.x >> 6;
    const int l16 = lane & 15, quad = lane >> 4;
    const int wm = wv >> 1, wn = wv & 1;
    int m0, n0;
    if (J.mode == 1) { m0 = blockIdx.y * 128; n0 = blockIdx.x * 128; }
    else             { m0 = blockIdx.x * 128; n0 = blockIdx.y * 128; }

    f32x4 acc[4][4] = {};

    for (int kk = 0; kk < KD; kk += 64) {
#pragma unroll
        for (int it = 0; it < 4; ++it) {
            int p0 = it * 256 + wv * 64;
            int p = p0 + lane;
            int row = p >> 3;
            int c = (p & 7) ^ (row & 7);
            gl_lds16(J.A + (size_t)(m0 + row) * KD + kk + c * 8, As + p0 * 8);
            gl_lds16(J.Bm + (size_t)(n0 + row) * KD + kk + c * 8, Bs + p0 * 8);
        }
        __syncthreads();
#pragma unroll
        for (int ks = 0; ks < 2; ++ks) {
            short8 a[4], b[4];
#pragma unroll
            for (int i = 0; i < 4; ++i) {
                int row = wm * 64 + i * 16 + l16;
                int pc = (ks * 4 + quad) ^ (row & 7);
                a[i] = *(const short8*)&As[row * 64 + pc * 8];
            }
#pragma unroll
            for (int j = 0; j < 4; ++j) {
                int row = wn * 64 + j * 16 + l16;
                int pc = (ks * 4 + quad) ^ (row & 7);
                b[j] = *(const short8*)&Bs[row * 64 + pc * 8];
            }
#pragma unroll
            for (int i = 0; i < 4; ++i)
#pragma unroll
                for (int j = 0; j < 4; ++j)
                    acc[i][j] = __builtin_amdgcn_mfma_f32_16x16x32_bf16(a[i], b[j], acc[i][j], 0, 0, 0);
        }
        __syncthreads();
    }

#pragma unroll
    for (int i = 0; i < 4; ++i) {
#pragma unroll
        for (int j = 0; j < 4; ++j) {
            int grow = m0 + wm * 64 + i * 16 + quad * 4;
            int gcol = n0 + wn * 64 + j * 16 + l16;
            if (J.mode == 0) {
                float bv = J.bias[gcol];
                int h = gcol >> 6, hd = gcol & 63;
                bf_t* dst = (bf_t*)J.out;
#pragma unroll
                for (int r = 0; r < 4; ++r) {
                    int row = grow + r;
                    int bI = row >> 12, s = row & 4095;
                    dst[(((size_t)(bI * Hh + h) * Sq + s) << 6) + hd] =
                        f2bf((acc[i][j][r] + bv) * J.scale);
                }
            } else if (J.mode == 1) {
                // V^T TILE-CONTIGUOUS layout: [bh][kv-tile][feat 64][key 64]
                bf_t* dst = (bf_t*)J.out;
                int t = gcol, bI = t >> 12, s = t & 4095;
                size_t tb = (size_t)(bI * Hh) * Sq * 64;   // h added per r
#pragma unroll
                for (int r = 0; r < 4; ++r) {
                    int f = grow + r;
                    int h = f >> 6, hd = f & 63;
                    dst[tb + (size_t)h * Sq * 64 + (s >> 6) * 4096 + hd * 64 + (s & 63)] =
                        f2bf(acc[i][j][r] + J.bias[f]);
                }
            } else {
                float bv = J.bias[gcol];
                float* dst = (float*)J.out;
#pragma unroll
                for (int r = 0; r < 4; ++r)
                    dst[(size_t)(grow + r) * Dm + gcol] = acc[i][j][r] + bv;
            }
        }
    }
}

// ---------------- flash attention, causal, fixed-shift softmax ----------------
// Q,K: [B*H, S, 64] bf16 (Q pre-scaled by (1/8)*log2e).
// VT: [B*H, Sq/64, 64 feat, 64 key] bf16 (tile-contiguous).
// R6/R9 structure (best measured: 139 µs): 64 q-rows/wave (NQ=4), block = 4
// waves = {row-group 0/1} x {key-split 0/1}, private register K/V loads with
// WAR prefetch, fixed-shift partials combined by pure addition via LDS.
// XCD swizzle retained (R9: null but harmless). FROZEN this round — control
// for the gemm/cvt A/B.
// NOTE: no min-occupancy arg in __launch_bounds__ (R3: (256,4) forced a
// 64-VGPR cap -> 2.3GB scratch spill).
#define SHIFT 18.0f
#define NQ 4

__global__ __launch_bounds__(256) void attn(const bf_t* __restrict__ Q,
                                            const bf_t* __restrict__ K,
                                            const bf_t* __restrict__ VT,
                                            bf_t* __restrict__ O) {
    // XCD-aware swizzle: each XCD gets 3 consecutive heads, all 32 q-tiles
    const int id = blockIdx.x + 24 * blockIdx.y;
    const int xcd = id & 7, slot = id >> 3;        // slot 0..95
    const int bh = xcd * 3 + slot % 3;
    const int qt = 31 - slot / 3;                  // long blocks first
    const int lane = threadIdx.x & 63, wv = threadIdx.x >> 6;   // wv 0..3
    const int rg = wv & 1, ksp = wv >> 1;          // row-group, key-split
    const int l16 = lane & 15, quad = lane >> 4;
    const int b = bh / Hh, h = bh % Hh;
    const size_t base = (size_t)bh * Sq * 64;
    const int q0 = qt * 128 + rg * 64;             // 64 rows per wave

    __shared__ float ocomb[2][64][68];             // [rg][row][feat] fp32, padded
    __shared__ float lcomb[2][64];

    const bf_t* __restrict__ Kb = K + base;
    const bf_t* __restrict__ Vb = VT + base;

    // Q as B-frags (n=qrow l16, k=quad*8+j)
    short8 qf[NQ][2];
#pragma unroll
    for (int i = 0; i < NQ; ++i) {
        const bf_t* qp = Q + base + (size_t)(q0 + i * 16 + l16) * 64 + quad * 8;
        qf[i][0] = *(const short8*)qp;
        qf[i][1] = *(const short8*)(qp + 32);
    }

    f32x4 oacc[NQ][4] = {};   // O^T: [i][feat quad*4+r] x [qrow l16]
    f32x4 lsum[NQ] = {};

    const int nkt = (q0 >> 6) + 1;
    const int hsp = (nkt + 1) >> 1;
    const int kt0 = ksp ? hsp : 0;
    const int kt1 = ksp ? nkt : hsp;

    const int kroff = ((l16 >> 2) << 3) + (l16 & 3);   // permuted row offset

    short8 ones32;
#pragma unroll
    for (int j = 0; j < 8; ++j) ones32[j] = (short)0x3F80;

    short8 kf[4][2];   // K tiles (permuted rows), t=2g+s
    short8 vfr[4][2];  // V frags [ot][g], 16B contiguous

    // 32-bit element offsets from Kb / Vb, advanced by constants per tile
    int ko = kroff * 64 + quad * 8 + kt0 * 4096;   // K: +(32g+4s)*64 per sub-tile
    int vo = l16 * 64 + quad * 8 + kt0 * 4096;     // V: +ot*1024 + 32g per frag

#define LOAD_K()                                                             \
    {                                                                        \
        _Pragma("unroll")                                                    \
        for (int g = 0; g < 2; ++g)                                          \
            _Pragma("unroll")                                                \
            for (int s = 0; s < 2; ++s) {                                    \
                const bf_t* kp = Kb + ko + (32 * g + 4 * s) * 64;            \
                kf[2 * g + s][0] = *(const short8*)kp;                       \
                kf[2 * g + s][1] = *(const short8*)(kp + 32);                \
            }                                                                \
    }
#define LOAD_V()                                                             \
    {                                                                        \
        _Pragma("unroll")                                                    \
        for (int ot = 0; ot < 4; ++ot)                                       \
            _Pragma("unroll")                                                \
            for (int g = 0; g < 2; ++g)                                      \
                vfr[ot][g] = *(const short8*)(Vb + vo + ot * 1024 + 32 * g); \
    }

    if (kt0 < kt1) { LOAD_K(); LOAD_V(); }

    for (int kt = kt0; kt < kt1; ++kt) {
        const int kv0 = kt * 64;
        const bool more = (kt + 1 < kt1);
#pragma unroll
        for (int i = 0; i < NQ; ++i) {
            // QK: S^T tiles, permuted key order; C-init carries the -SHIFT
            f32x4 st[4];
#pragma unroll
            for (int t = 0; t < 4; ++t) {
                f32x4 z = {-SHIFT, -SHIFT, -SHIFT, -SHIFT};
                z = __builtin_amdgcn_mfma_f32_16x16x32_bf16(kf[t][0], qf[i][0], z, 0, 0, 0);
                st[t] = __builtin_amdgcn_mfma_f32_16x16x32_bf16(kf[t][1], qf[i][1], z, 0, 0, 0);
            }
            if (i == NQ - 1) { ko += 4096; if (more) LOAD_K(); }   // WAR: after last QK use

            // mask + exp2 + pack (permuted key = kv0+32g+8*quad+4s+r)
            alignas(16) unsigned int pkd[4][2];
            const bool need_mask = (kv0 + 63 > q0 + i * 16);
#pragma unroll
            for (int t = 0; t < 4; ++t) {
                int g = t >> 1, s = t & 1;
                f32x4 sv = st[t];
                if (need_mask) {
                    int qrow = q0 + i * 16 + l16;
                    int kb2 = kv0 + 32 * g + 8 * quad + 4 * s;
#pragma unroll
                    for (int r = 0; r < 4; ++r)
                        if (kb2 + r > qrow) sv[r] = -1e30f;
                }
                pkd[t][0] = pk2bf(fexp2(sv[0]), fexp2(sv[1]));
                pkd[t][1] = pk2bf(fexp2(sv[2]), fexp2(sv[3]));
            }
            // PV: B-frag direct from pkd, K=32
#pragma unroll
            for (int g = 0; g < 2; ++g) {
                short8 pf = *(const short8*)&pkd[2 * g][0];
                lsum[i] = __builtin_amdgcn_mfma_f32_16x16x32_bf16(ones32, pf, lsum[i], 0, 0, 0);
#pragma unroll
                for (int ot = 0; ot < 4; ++ot)
                    oacc[i][ot] = __builtin_amdgcn_mfma_f32_16x16x32_bf16(vfr[ot][g], pf, oacc[i][ot], 0, 0, 0);
            }
        }
        vo += 4096;
        if (more) LOAD_V();   // WAR: issues after PV, lands during next QK+exp
    }
#undef LOAD_K
#undef LOAD_V

    // combine partials: split-1 writes, barrier, split-0 adds + epilogue
    if (ksp) {
#pragma unroll
        for (int i = 0; i < NQ; ++i) {
            int row = i * 16 + l16;
#pragma unroll
            for (int ot = 0; ot < 4; ++ot)
                *(f32x4*)&ocomb[rg][row][ot * 16 + quad * 4] = oacc[i][ot];
            if (quad == 0) lcomb[rg][row] = lsum[i][0];
        }
    }
    __syncthreads();
    if (!ksp) {
#pragma unroll
        for (int i = 0; i < NQ; ++i) {
            int row = i * 16 + l16;
            float ls = lsum[i][0] + lcomb[rg][row];
            float inv = 1.0f / ls;
            int srow = q0 + row;
            bf_t* orow = O + (size_t)(b * Sq + srow) * Dm + h * 64;
#pragma unroll
            for (int ot = 0; ot < 4; ++ot) {
                f32x4 oc = *(const f32x4*)&ocomb[rg][row][ot * 16 + quad * 4];
                uint2 pk;
                pk.x = pk2bf((oacc[i][ot][0] + oc[0]) * inv, (oacc[i][ot][1] + oc[1]) * inv);
                pk.y = pk2bf((oacc[i][ot][2] + oc[2]) * inv, (oacc[i][ot][3] + oc[3]) * inv);
                *(uint2*)(orow + ot * 16 + quad * 4) = pk;
            }
        }
    }
}

extern "C" void kernel_launch(void* const* d_in, const int* in_sizes, int n_in,
                              void* d_out, int out_size, void* d_ws, size_t ws_size,
                              hipStream_t stream) {
    const float* q  = (const float*)d_in[0];
    const float* k  = (const float*)d_in[1];
    const float* v  = (const float*)d_in[2];
    // d_in[3]: causal mask — analytic
    const float* Wq = (const float*)d_in[4];  const float* bq = (const float*)d_in[5];
    const float* Wk = (const float*)d_in[6];  const float* bk = (const float*)d_in[7];
    const float* Wv = (const float*)d_in[8];  const float* bv = (const float*)d_in[9];
    const float* Wo = (const float*)d_in[10]; const float* bo = (const float*)d_in[11];
    float* out = (float*)d_out;

    const float QSCALE = 0.125f * 1.44269504f;     // (1/sqrt(64)) * log2(e)

    const size_t NTOK = (size_t)2 * Sq * Dm;   // 6291456
    const size_t NW   = (size_t)Dm * Dm;       // 589824
    dim3 b256(256);

    const size_t need_main = (6 * NTOK + 4 * NW) * 2;   // 80.2 MB

    if (ws_size >= need_main) {
        bf_t* qb  = (bf_t*)d_ws;
        bf_t* kb  = qb + NTOK;
        bf_t* vb  = kb + NTOK;
        bf_t* xq  = vb + NTOK;
        bf_t* xk  = xq + NTOK;
        bf_t* xv  = xk + NTOK;
        bf_t* wqb = xv + NTOK;
        bf_t* wkb = wqb + NW;
        bf_t* wvb = wkb + NW;
        bf_t* wob = wvb + NW;
        bf_t* ob  = xq;

        // one merged cvt launch: 3 big input jobs + 4 small weight jobs
        CvtJobs cj = {{q, k, v, Wq, Wk, Wv, Wo, q},
                      {xq, xk, xv, wqb, wkb, wvb, wob, xq},
                      {(int)NTOK, (int)NTOK, (int)NTOK,
                       (int)NW, (int)NW, (int)NW, (int)NW, 0}};
        cvt<<<dim3(3072, 1, 7), b256, 0, stream>>>(cj);

        GemmJobs gp;
        gp.j[0] = {xq,  wqb, bq, qb, 0, QSCALE};
        gp.j[1] = {xk,  wkb, bk, kb, 0, 1.0f};
        gp.j[2] = {wvb, xv,  bv, vb, 1, 1.0f};     // V^T direct (tile-contiguous)
        gemm_k<<<dim3(64, 6, 3), b256, 0, stream>>>(gp);

        attn<<<dim3(2 * Hh, Sq / 128), b256, 0, stream>>>(qb, kb, vb, ob);

        GemmJobs go;
        go.j[0] = {ob, wob, bo, out, 2, 1.0f};
        go.j[1] = go.j[0]; go.j[2] = go.j[0];
        gemm_k<<<dim3(64, 6, 1), b256, 0, stream>>>(go);
    } else {
        bf_t* qb  = (bf_t*)d_ws;
        bf_t* kb  = qb + NTOK;
        bf_t* vb  = kb + NTOK;
        bf_t* ob  = vb + NTOK;
        bf_t* xc  = ob + NTOK;
        bf_t* wqb = xc + NTOK;
        bf_t* wkb = wqb + NW;
        bf_t* wvb = wkb + NW;
        bf_t* wob = wvb + NW;

        CvtJobs cw = {{Wq, Wk, Wv, Wo, Wq, Wq, Wq, Wq},
                      {wqb, wkb, wvb, wob, wqb, wqb, wqb, wqb},
                      {(int)NW, (int)NW, (int)NW, (int)NW, 0, 0, 0, 0}};
        cvt<<<dim3(288, 1, 4), b256, 0, stream>>>(cw);

        GemmJobs gj;
        CvtJobs c1 = {{q}, {xc}, {(int)NTOK}};
        cvt<<<dim3(3072, 1, 1), b256, 0, stream>>>(c1);
        gj.j[0] = {xc, wqb, bq, qb, 0, QSCALE}; gj.j[1] = gj.j[0]; gj.j[2] = gj.j[0];
        gemm_k<<<dim3(64, 6, 1), b256, 0, stream>>>(gj);

        CvtJobs c2 = {{k}, {xc}, {(int)NTOK}};
        cvt<<<dim3(3072, 1, 1), b256, 0, stream>>>(c2);
        gj.j[0] = {xc, wkb, bk, kb, 0, 1.0f}; gj.j[1] = gj.j[0]; gj.j[2] = gj.j[0];
        gemm_k<<<dim3(64, 6, 1), b256, 0, stream>>>(gj);

        CvtJobs c3 = {{v}, {xc}, {(int)NTOK}};
        cvt<<<dim3(3072, 1, 1), b256, 0, stream>>>(c3);
        gj.j[0] = {wvb, xc, bv, vb, 1, 1.0f}; gj.j[1] = gj.j[0]; gj.j[2] = gj.j[0];
        gemm_k<<<dim3(64, 6, 1), b256, 0, stream>>>(gj);

        attn<<<dim3(2 * Hh, Sq / 128), b256, 0, stream>>>(qb, kb, vb, ob);

        gj.j[0] = {ob, wob, bo, out, 2, 1.0f}; gj.j[1] = gj.j[0]; gj.j[2] = gj.j[0];
        gemm_k<<<dim3(64, 6, 1), b256, 0, stream>>>(gj);
    }
}

// Round 11
// 356.389 us; speedup vs baseline: 1.1881x; 1.0268x over previous
//
#include <hip/hip_runtime.h>

// B=2, S=4096, D=768, H=12, HD=64
#define Sq 4096
#define Dm 768
#define Hh 12
#define KD 768

typedef short short8 __attribute__((ext_vector_type(8)));
typedef float f32x4 __attribute__((ext_vector_type(4)));
typedef unsigned short bf_t;

__device__ inline bf_t f2bf(float f) {
    unsigned int u = __builtin_bit_cast(unsigned int, f);
    u += 0x7fffu + ((u >> 16) & 1u);   // RNE
    return (bf_t)(u >> 16);
}

// pack two fp32 -> bf16x2 (round-half-up: 1 add each + 1 v_perm) — HW-verified path
__device__ inline unsigned int pk2bf(float a, float b) {
    unsigned int ua = __builtin_bit_cast(unsigned int, a) + 0x8000u;
    unsigned int ub = __builtin_bit_cast(unsigned int, b) + 0x8000u;
    return __builtin_amdgcn_perm(ub, ua, 0x07060302);
}

__device__ inline float fexp2(float x) {
#if __has_builtin(__builtin_amdgcn_exp2f)
    return __builtin_amdgcn_exp2f(x);
#else
    return exp2f(x);
#endif
}

__device__ inline void gl_lds16(const void* g, void* l) {
    __builtin_amdgcn_global_load_lds(
        (const __attribute__((address_space(1))) unsigned int*)g,
        (__attribute__((address_space(3))) unsigned int*)l, 16, 0, 0);
}

// ---------------- fp32 -> bf16 convert, up to 8 arrays per launch ----------------
struct CvtJobs { const float* s[8]; bf_t* d[8]; int n[8]; };

__global__ __launch_bounds__(256) void cvt(CvtJobs jobs) {
    const float* s = jobs.s[blockIdx.z];
    bf_t* d = jobs.d[blockIdx.z];
    int n = jobs.n[blockIdx.z];
    int i = (blockIdx.x * 256 + threadIdx.x) * 8;
    if (i < n) {
        float4 a = *(const float4*)(s + i);
        float4 b = *(const float4*)(s + i + 4);
        short8 p;
        p[0] = (short)f2bf(a.x); p[1] = (short)f2bf(a.y);
        p[2] = (short)f2bf(a.z); p[3] = (short)f2bf(a.w);
        p[4] = (short)f2bf(b.x); p[5] = (short)f2bf(b.y);
        p[6] = (short)f2bf(b.z); p[7] = (short)f2bf(b.w);
        *(short8*)(d + i) = p;
    }
}

// ---------------- bf16 GEMM: C = A (MxK) * B^T (NxK) + bias ----------------
// mode 0: Q -> standard [bh][s][64] (scaled)
// mode 3: K -> FRAGMENT-PACKED [bh][kt][t][half][lane][8]
// mode 1: V -> FRAGMENT-PACKED [bh][kt][g*4+ot][lane][8]
// mode 2: fp32 out [row][Dm]
struct GemmJob {
    const bf_t* __restrict__ A; const bf_t* __restrict__ Bm;
    const float* __restrict__ bias; void* __restrict__ out;
    int mode; float scale;
};
struct GemmJobs { GemmJob j[3]; };

__global__ __launch_bounds__(256) void gemm_k(GemmJobs jobs) {
    const GemmJob J = jobs.j[blockIdx.z];
    __shared__ bf_t As[128 * 64];
    __shared__ bf_t Bs[128 * 64];
    const int lane = threadIdx.x & 63, wv = threadIdx.x >> 6;
    const int l16 = lane & 15, quad = lane >> 4;
    const int wm = wv >> 1, wn = wv & 1;
    int m0, n0;
    if (J.mode == 1) { m0 = blockIdx.y * 128; n0 = blockIdx.x * 128; }
    else             { m0 = blockIdx.x * 128; n0 = blockIdx.y * 128; }

    f32x4 acc[4][4] = {};

    for (int kk = 0; kk < KD; kk += 64) {
#pragma unroll
        for (int it = 0; it < 4; ++it) {
            int p0 = it * 256 + wv * 64;
            int p = p0 + lane;
            int row = p >> 3;
            int c = (p & 7) ^ (row & 7);
            gl_lds16(J.A + (size_t)(m0 + row) * KD + kk + c * 8, As + p0 * 8);
            gl_lds16(J.Bm + (size_t)(n0 + row) * KD + kk + c * 8, Bs + p0 * 8);
        }
        __syncthreads();
#pragma unroll
        for (int ks = 0; ks < 2; ++ks) {
            short8 a[4], b[4];
#pragma unroll
            for (int i = 0; i < 4; ++i) {
                int row = wm * 64 + i * 16 + l16;
                int pc = (ks * 4 + quad) ^ (row & 7);
                a[i] = *(const short8*)&As[row * 64 + pc * 8];
            }
#pragma unroll
            for (int j = 0; j < 4; ++j) {
                int row = wn * 64 + j * 16 + l16;
                int pc = (ks * 4 + quad) ^ (row & 7);
                b[j] = *(const short8*)&Bs[row * 64 + pc * 8];
            }
#pragma unroll
            for (int i = 0; i < 4; ++i)
#pragma unroll
                for (int j = 0; j < 4; ++j)
                    acc[i][j] = __builtin_amdgcn_mfma_f32_16x16x32_bf16(a[i], b[j], acc[i][j], 0, 0, 0);
        }
        __syncthreads();
    }

#pragma unroll
    for (int i = 0; i < 4; ++i) {
#pragma unroll
        for (int j = 0; j < 4; ++j) {
            int grow = m0 + wm * 64 + i * 16 + quad * 4;
            int gcol = n0 + wn * 64 + j * 16 + l16;
            if (J.mode == 0) {
                float bv = J.bias[gcol];
                int h = gcol >> 6, hd = gcol & 63;
                bf_t* dst = (bf_t*)J.out;
#pragma unroll
                for (int r = 0; r < 4; ++r) {
                    int row = grow + r;
                    int bI = row >> 12, s = row & 4095;
                    dst[(((size_t)(bI * Hh + h) * Sq + s) << 6) + hd] =
                        f2bf((acc[i][j][r] + bv) * J.scale);
                }
            } else if (J.mode == 3) {
                // K fragment-packed: [bh][kt][t=2g+s2][h2][lane][8]
                // packed(t,h2,lane,j) = K[32g+4*s2+8*(l16>>2)+(l16&3), qd*8+32*h2+j]
                float bv = J.bias[gcol];
                int hh = gcol >> 6, hd = gcol & 63;
                int h2 = hd >> 5, rem = hd & 31, qd = rem >> 3, j2 = rem & 7;
                bf_t* dst = (bf_t*)J.out;
#pragma unroll
                for (int r = 0; r < 4; ++r) {
                    int row = grow + r;
                    int bI = row >> 12, s = row & 4095;
                    int kt2 = s >> 6, rr = s & 63;
                    int g2 = rr >> 5, r5 = rr & 31;
                    int a2 = r5 >> 3, s22 = (r5 >> 2) & 1, b2 = r5 & 3;
                    int lane2 = qd * 16 + (4 * a2 + b2);
                    dst[(size_t)(bI * Hh + hh) * Sq * 64 +
                        kt2 * 4096 + (2 * g2 + s22) * 1024 + h2 * 512 + lane2 * 8 + j2] =
                        f2bf(acc[i][j][r] + bv);
                }
            } else if (J.mode == 1) {
                // V fragment-packed: [bh][kt][g*4+ot][lane][8]
                // packed(g,ot,lane,j) = V^T[ot*16+l16, 32g+qd*8+j]
                bf_t* dst = (bf_t*)J.out;
                int t = gcol, bI = t >> 12, s = t & 4095;
                int kt2 = s >> 6, rr = s & 63;
                int g2 = rr >> 5, qd = (rr & 31) >> 3, j2 = rr & 7;
#pragma unroll
                for (int r = 0; r < 4; ++r) {
                    int f = grow + r;
                    int hh = f >> 6, hd = f & 63;
                    int ot = hd >> 4, l16v = hd & 15;
                    int lane2 = qd * 16 + l16v;
                    dst[(size_t)(bI * Hh + hh) * Sq * 64 +
                        kt2 * 4096 + (g2 * 4 + ot) * 512 + lane2 * 8 + j2] =
                        f2bf(acc[i][j][r] + J.bias[f]);
                }
            } else {
                float bv = J.bias[gcol];
                float* dst = (float*)J.out;
#pragma unroll
                for (int r = 0; r < 4; ++r)
                    dst[(size_t)(grow + r) * Dm + gcol] = acc[i][j][r] + bv;
            }
        }
    }
}

// ---------------- flash attention, causal, fixed-shift softmax ----------------
// Q: [B*H, S, 64] bf16 (pre-scaled by (1/8)*log2e). K/VT: FRAGMENT-PACKED
// (see gemm modes 3/1) so every K/V load is a fully-coalesced 1KB burst
// (lane*16B linear) instead of the former 16-segment gather — R0..R10
// established attn dur ∝ VMEM transaction work; this halves it.
// Register contents are bit-identical to the proven permuted-fragment kernel;
// mask/PV/combine formulas unchanged. R6/R9 structure: 64 q-rows/wave (NQ=4),
// block = 4 waves = {row-group 0/1} x {key-split 0/1}, fixed-shift partials
// combined by pure addition via LDS. XCD swizzle retained.
// NOTE: no min-occupancy arg in __launch_bounds__ (R3: (256,4) forced a
// 64-VGPR cap -> 2.3GB scratch spill).
#define SHIFT 18.0f
#define NQ 4

__global__ __launch_bounds__(256) void attn(const bf_t* __restrict__ Q,
                                            const bf_t* __restrict__ K,
                                            const bf_t* __restrict__ VT,
                                            bf_t* __restrict__ O) {
    // XCD-aware swizzle: each XCD gets 3 consecutive heads, all 32 q-tiles
    const int id = blockIdx.x + 24 * blockIdx.y;
    const int xcd = id & 7, slot = id >> 3;        // slot 0..95
    const int bh = xcd * 3 + slot % 3;
    const int qt = 31 - slot / 3;                  // long blocks first
    const int lane = threadIdx.x & 63, wv = threadIdx.x >> 6;   // wv 0..3
    const int rg = wv & 1, ksp = wv >> 1;          // row-group, key-split
    const int l16 = lane & 15, quad = lane >> 4;
    const int b = bh / Hh, h = bh % Hh;
    const size_t base = (size_t)bh * Sq * 64;
    const int q0 = qt * 128 + rg * 64;             // 64 rows per wave

    __shared__ float ocomb[2][64][68];             // [rg][row][feat] fp32, padded
    __shared__ float lcomb[2][64];

    const bf_t* __restrict__ Kb = K + base;
    const bf_t* __restrict__ Vb = VT + base;

    // Q as B-frags (n=qrow l16, k=quad*8+j)
    short8 qf[NQ][2];
#pragma unroll
    for (int i = 0; i < NQ; ++i) {
        const bf_t* qp = Q + base + (size_t)(q0 + i * 16 + l16) * 64 + quad * 8;
        qf[i][0] = *(const short8*)qp;
        qf[i][1] = *(const short8*)(qp + 32);
    }

    f32x4 oacc[NQ][4] = {};   // O^T: [i][feat quad*4+r] x [qrow l16]
    f32x4 lsum[NQ] = {};

    const int nkt = (q0 >> 6) + 1;
    const int hsp = (nkt + 1) >> 1;
    const int kt0 = ksp ? hsp : 0;
    const int kt1 = ksp ? nkt : hsp;

    short8 ones32;
#pragma unroll
    for (int j = 0; j < 8; ++j) ones32[j] = (short)0x3F80;

    short8 kf[4][2];   // K tiles (permuted rows), t=2g+s
    short8 vfr[4][2];  // V frags [ot][g]

    // coalesced element offsets: lane*8 within each 512-elem packed group
    int ko = kt0 * 4096 + lane * 8;
    int vo = kt0 * 4096 + lane * 8;

#define LOAD_K()                                                             \
    {                                                                        \
        _Pragma("unroll")                                                    \
        for (int t = 0; t < 4; ++t) {                                        \
            kf[t][0] = *(const short8*)(Kb + ko + t * 1024);                 \
            kf[t][1] = *(const short8*)(Kb + ko + t * 1024 + 512);           \
        }                                                                    \
    }
#define LOAD_V()                                                             \
    {                                                                        \
        _Pragma("unroll")                                                    \
        for (int ot = 0; ot < 4; ++ot)                                       \
            _Pragma("unroll")                                                \
            for (int g = 0; g < 2; ++g)                                      \
                vfr[ot][g] = *(const short8*)(Vb + vo + (g * 4 + ot) * 512); \
    }

    if (kt0 < kt1) { LOAD_K(); LOAD_V(); }

    for (int kt = kt0; kt < kt1; ++kt) {
        const int kv0 = kt * 64;
        const bool more = (kt + 1 < kt1);
#pragma unroll
        for (int i = 0; i < NQ; ++i) {
            // QK: S^T tiles, permuted key order; C-init carries the -SHIFT
            f32x4 st[4];
#pragma unroll
            for (int t = 0; t < 4; ++t) {
                f32x4 z = {-SHIFT, -SHIFT, -SHIFT, -SHIFT};
                z = __builtin_amdgcn_mfma_f32_16x16x32_bf16(kf[t][0], qf[i][0], z, 0, 0, 0);
                st[t] = __builtin_amdgcn_mfma_f32_16x16x32_bf16(kf[t][1], qf[i][1], z, 0, 0, 0);
            }
            if (i == NQ - 1) { ko += 4096; if (more) LOAD_K(); }   // WAR: after last QK use

            // mask + exp2 + pack (permuted key = kv0+32g+8*quad+4s+r)
            alignas(16) unsigned int pkd[4][2];
            const bool need_mask = (kv0 + 63 > q0 + i * 16);
#pragma unroll
            for (int t = 0; t < 4; ++t) {
                int g = t >> 1, s = t & 1;
                f32x4 sv = st[t];
                if (need_mask) {
                    int qrow = q0 + i * 16 + l16;
                    int kb2 = kv0 + 32 * g + 8 * quad + 4 * s;
#pragma unroll
                    for (int r = 0; r < 4; ++r)
                        if (kb2 + r > qrow) sv[r] = -1e30f;
                }
                pkd[t][0] = pk2bf(fexp2(sv[0]), fexp2(sv[1]));
                pkd[t][1] = pk2bf(fexp2(sv[2]), fexp2(sv[3]));
            }
            // PV: B-frag direct from pkd, K=32
#pragma unroll
            for (int g = 0; g < 2; ++g) {
                short8 pf = *(const short8*)&pkd[2 * g][0];
                lsum[i] = __builtin_amdgcn_mfma_f32_16x16x32_bf16(ones32, pf, lsum[i], 0, 0, 0);
#pragma unroll
                for (int ot = 0; ot < 4; ++ot)
                    oacc[i][ot] = __builtin_amdgcn_mfma_f32_16x16x32_bf16(vfr[ot][g], pf, oacc[i][ot], 0, 0, 0);
            }
        }
        vo += 4096;
        if (more) LOAD_V();   // WAR: issues after PV, lands during next QK+exp
    }
#undef LOAD_K
#undef LOAD_V

    // combine partials: split-1 writes, barrier, split-0 adds + epilogue
    if (ksp) {
#pragma unroll
        for (int i = 0; i < NQ; ++i) {
            int row = i * 16 + l16;
#pragma unroll
            for (int ot = 0; ot < 4; ++ot)
                *(f32x4*)&ocomb[rg][row][ot * 16 + quad * 4] = oacc[i][ot];
            if (quad == 0) lcomb[rg][row] = lsum[i][0];
        }
    }
    __syncthreads();
    if (!ksp) {
#pragma unroll
        for (int i = 0; i < NQ; ++i) {
            int row = i * 16 + l16;
            float ls = lsum[i][0] + lcomb[rg][row];
            float inv = 1.0f / ls;
            int srow = q0 + row;
            bf_t* orow = O + (size_t)(b * Sq + srow) * Dm + h * 64;
#pragma unroll
            for (int ot = 0; ot < 4; ++ot) {
                f32x4 oc = *(const f32x4*)&ocomb[rg][row][ot * 16 + quad * 4];
                uint2 pk;
                pk.x = pk2bf((oacc[i][ot][0] + oc[0]) * inv, (oacc[i][ot][1] + oc[1]) * inv);
                pk.y = pk2bf((oacc[i][ot][2] + oc[2]) * inv, (oacc[i][ot][3] + oc[3]) * inv);
                *(uint2*)(orow + ot * 16 + quad * 4) = pk;
            }
        }
    }
}

extern "C" void kernel_launch(void* const* d_in, const int* in_sizes, int n_in,
                              void* d_out, int out_size, void* d_ws, size_t ws_size,
                              hipStream_t stream) {
    const float* q  = (const float*)d_in[0];
    const float* k  = (const float*)d_in[1];
    const float* v  = (const float*)d_in[2];
    // d_in[3]: causal mask — analytic
    const float* Wq = (const float*)d_in[4];  const float* bq = (const float*)d_in[5];
    const float* Wk = (const float*)d_in[6];  const float* bk = (const float*)d_in[7];
    const float* Wv = (const float*)d_in[8];  const float* bv = (const float*)d_in[9];
    const float* Wo = (const float*)d_in[10]; const float* bo = (const float*)d_in[11];
    float* out = (float*)d_out;

    const float QSCALE = 0.125f * 1.44269504f;     // (1/sqrt(64)) * log2(e)

    const size_t NTOK = (size_t)2 * Sq * Dm;   // 6291456
    const size_t NW   = (size_t)Dm * Dm;       // 589824
    dim3 b256(256);

    const size_t need_main = (6 * NTOK + 4 * NW) * 2;   // 80.2 MB

    if (ws_size >= need_main) {
        bf_t* qb  = (bf_t*)d_ws;
        bf_t* kb  = qb + NTOK;
        bf_t* vb  = kb + NTOK;
        bf_t* xq  = vb + NTOK;
        bf_t* xk  = xq + NTOK;
        bf_t* xv  = xk + NTOK;
        bf_t* wqb = xv + NTOK;
        bf_t* wkb = wqb + NW;
        bf_t* wvb = wkb + NW;
        bf_t* wob = wvb + NW;
        bf_t* ob  = xq;

        // one merged cvt launch: 3 big input jobs + 4 small weight jobs
        CvtJobs cj = {{q, k, v, Wq, Wk, Wv, Wo, q},
                      {xq, xk, xv, wqb, wkb, wvb, wob, xq},
                      {(int)NTOK, (int)NTOK, (int)NTOK,
                       (int)NW, (int)NW, (int)NW, (int)NW, 0}};
        cvt<<<dim3(3072, 1, 7), b256, 0, stream>>>(cj);

        GemmJobs gp;
        gp.j[0] = {xq,  wqb, bq, qb, 0, QSCALE};
        gp.j[1] = {xk,  wkb, bk, kb, 3, 1.0f};     // K fragment-packed
        gp.j[2] = {wvb, xv,  bv, vb, 1, 1.0f};     // V fragment-packed
        gemm_k<<<dim3(64, 6, 3), b256, 0, stream>>>(gp);

        attn<<<dim3(2 * Hh, Sq / 128), b256, 0, stream>>>(qb, kb, vb, ob);

        GemmJobs go;
        go.j[0] = {ob, wob, bo, out, 2, 1.0f};
        go.j[1] = go.j[0]; go.j[2] = go.j[0];
        gemm_k<<<dim3(64, 6, 1), b256, 0, stream>>>(go);
    } else {
        bf_t* qb  = (bf_t*)d_ws;
        bf_t* kb  = qb + NTOK;
        bf_t* vb  = kb + NTOK;
        bf_t* ob  = vb + NTOK;
        bf_t* xc  = ob + NTOK;
        bf_t* wqb = xc + NTOK;
        bf_t* wkb = wqb + NW;
        bf_t* wvb = wkb + NW;
        bf_t* wob = wvb + NW;

        CvtJobs cw = {{Wq, Wk, Wv, Wo, Wq, Wq, Wq, Wq},
                      {wqb, wkb, wvb, wob, wqb, wqb, wqb, wqb},
                      {(int)NW, (int)NW, (int)NW, (int)NW, 0, 0, 0, 0}};
        cvt<<<dim3(288, 1, 4), b256, 0, stream>>>(cw);

        GemmJobs gj;
        CvtJobs c1 = {{q}, {xc}, {(int)NTOK}};
        cvt<<<dim3(3072, 1, 1), b256, 0, stream>>>(c1);
        gj.j[0] = {xc, wqb, bq, qb, 0, QSCALE}; gj.j[1] = gj.j[0]; gj.j[2] = gj.j[0];
        gemm_k<<<dim3(64, 6, 1), b256, 0, stream>>>(gj);

        CvtJobs c2 = {{k}, {xc}, {(int)NTOK}};
        cvt<<<dim3(3072, 1, 1), b256, 0, stream>>>(c2);
        gj.j[0] = {xc, wkb, bk, kb, 3, 1.0f}; gj.j[1] = gj.j[0]; gj.j[2] = gj.j[0];
        gemm_k<<<dim3(64, 6, 1), b256, 0, stream>>>(gj);

        CvtJobs c3 = {{v}, {xc}, {(int)NTOK}};
        cvt<<<dim3(3072, 1, 1), b256, 0, stream>>>(c3);
        gj.j[0] = {wvb, xc, bv, vb, 1, 1.0f}; gj.j[1] = gj.j[0]; gj.j[2] = gj.j[0];
        gemm_k<<<dim3(64, 6, 1), b256, 0, stream>>>(gj);

        attn<<<dim3(2 * Hh, Sq / 128), b256, 0, stream>>>(qb, kb, vb, ob);

        gj.j[0] = {ob, wob, bo, out, 2, 1.0f}; gj.j[1] = gj.j[0]; gj.j[2] = gj.j[0];
        gemm_k<<<dim3(64, 6, 1), b256, 0, stream>>>(gj);
    }
}